// Round 3
// baseline (116.104 us; speedup 1.0000x reference)
//
#include <hip/hip_runtime.h>

// Problem: A=8, B=16, N=M=1024, K=64. u:(A,B,N,K) f32, v:(A,B,M,K) f32.
// out0 = u * (dot(u_row, v_sum) > 0), out1 = v * (dot(v_row, u_sum) > 0)
//
// Round-6: read-once via PAIRWISE block exchange (no cooperative launch —
// round 5's hipLaunchCooperativeKernel killed the container, presumably the
// graph-capture path). Block (batch,half) reads only its own half (256 KB,
// -> registers), publishes its 128-float partial colsum to ws with
// agent-scope atomics + a release fetch_add on its flag, then thread 0
// spins (bounded) on the partner's flag. Seqno protocol (flag delta vs a
// snapshot taken at kernel start) survives ws re-poisoning between graph
// replays. On spin timeout: fall back to reading the partner half directly
// (round-1 behavior) — deadlock-proof by construction since publication
// precedes waiting.
//   reads issued = 67 MB, writes = 67 MB (+tiny ws traffic).
// Floor: 134 MB / 6.3 TB/s = 21.3 us + ~2 us exchange.

#define NBATCH 128        // A*B
#define NROW   1024       // N == M
#define KDIM   64
#define ELEMS_PER_TENSOR (128ull * 1024ull * 64ull)  // 8388608

// ws layout: payload [batch][half][which][64 floats] then 256 uint flags
#define WS_PAYLOAD_FLOATS (NBATCH * 2 * 2 * 64)      // 32768 floats = 128 KB
#define WS_FLAGS (NBATCH * 2)                        // 256
#define WS_BYTES ((size_t)WS_PAYLOAD_FLOATS * 4 + (size_t)WS_FLAGS * 4)

#define SPIN_LIMIT 65536u   // ~10-30 ms worst case; legit waits are ~0

typedef float floatx4 __attribute__((ext_vector_type(4)));  // for nontemporal builtin

__global__ __launch_bounds__(1024)
void fused_pair_kernel(const float* __restrict__ u,
                       const float* __restrict__ v,
                       float* __restrict__ out,
                       float* __restrict__ wsf,
                       unsigned int* __restrict__ flags) {
    const int bid   = blockIdx.x;        // 0..255 (1 block/CU)
    // Same-XCD pair swizzle: pair blocks are bids (i, i+8) -> same L2.
    const int xcd   = bid & 7;
    const int slot  = bid >> 3;          // 0..31
    const int batch = xcd * 16 + (slot >> 1);  // 0..127
    const int half  = slot & 1;          // own rows: [half*512, half*512+512)
    const int tid   = threadIdx.x;       // 0..1023
    const int k4    = tid & 15;          // float4 column group
    const int rg    = tid >> 4;          // 0..63 row group
    const int wave  = tid >> 6;          // 0..15
    const int my_slot  = batch * 2 + half;
    const int oth_slot = batch * 2 + (1 - half);

    // Snapshot partner's flag BEFORE Phase A (syncthreads pins the atomic so
    // the compiler can't sink it past our own publish).
    unsigned int base = 0u;
    if (tid == 0)
        base = __hip_atomic_load(&flags[oth_slot], __ATOMIC_RELAXED,
                                 __HIP_MEMORY_SCOPE_AGENT);
    __syncthreads();

    const float4* ub = (const float4*)(u + (size_t)batch * NROW * KDIM);
    const float4* vb = (const float4*)(v + (size_t)batch * NROW * KDIM);

    // ---- Phase A: read OWN half only -> registers + partial col sums ------
    const int r_own0 = half * 512 + rg;

    float4 ur[8], vr[8];
    float4 su = make_float4(0.f, 0.f, 0.f, 0.f);
    float4 sv = make_float4(0.f, 0.f, 0.f, 0.f);
    #pragma unroll
    for (int i = 0; i < 8; ++i) {
        size_t io = (size_t)(r_own0 + 64 * i) * 16 + k4;  // wave: 4 rows x 1KB, coalesced
        ur[i] = ub[io];
        vr[i] = vb[io];
        su.x += ur[i].x; su.y += ur[i].y; su.z += ur[i].z; su.w += ur[i].w;
        sv.x += vr[i].x; sv.y += vr[i].y; sv.z += vr[i].z; sv.w += vr[i].w;
    }

    // ---- Reduce col sums: shfl across the 4 row-groups within each wave ----
    su.x += __shfl_xor(su.x, 16); su.y += __shfl_xor(su.y, 16);
    su.z += __shfl_xor(su.z, 16); su.w += __shfl_xor(su.w, 16);
    su.x += __shfl_xor(su.x, 32); su.y += __shfl_xor(su.y, 32);
    su.z += __shfl_xor(su.z, 32); su.w += __shfl_xor(su.w, 32);
    sv.x += __shfl_xor(sv.x, 16); sv.y += __shfl_xor(sv.y, 16);
    sv.z += __shfl_xor(sv.z, 16); sv.w += __shfl_xor(sv.w, 16);
    sv.x += __shfl_xor(sv.x, 32); sv.y += __shfl_xor(sv.y, 32);
    sv.z += __shfl_xor(sv.z, 32); sv.w += __shfl_xor(sv.w, 32);

    __shared__ float4 red_u[16][16];   // [wave][k4]
    __shared__ float4 red_v[16][16];
    __shared__ float4 fsum_own[2][16]; // [0]=v colsum partial, [1]=u colsum partial
    __shared__ float4 fsum_oth[2][16];
    __shared__ int sh_timeout;
    if ((tid & 63) < 16) {             // lane 0..15 holds k4 = lane
        red_u[wave][k4] = su;
        red_v[wave][k4] = sv;
    }
    __syncthreads();

    // Own-half partial colsum -> shared + publish to ws (disjoint slots).
    if (tid < 32) {
        const int which = tid >> 4;    // 0 -> v colsum, 1 -> u colsum
        const int c     = tid & 15;
        float4 t = make_float4(0.f, 0.f, 0.f, 0.f);
        if (which == 0) {
            #pragma unroll
            for (int i = 0; i < 16; ++i) {
                float4 b = red_v[i][c];
                t.x += b.x; t.y += b.y; t.z += b.z; t.w += b.w;
            }
        } else {
            #pragma unroll
            for (int i = 0; i < 16; ++i) {
                float4 a = red_u[i][c];
                t.x += a.x; t.y += a.y; t.z += a.z; t.w += a.w;
            }
        }
        fsum_own[which][c] = t;
        float* dst = wsf + ((size_t)my_slot * 2 + which) * 64 + c * 4;
        __hip_atomic_store(dst + 0, t.x, __ATOMIC_RELAXED, __HIP_MEMORY_SCOPE_AGENT);
        __hip_atomic_store(dst + 1, t.y, __ATOMIC_RELAXED, __HIP_MEMORY_SCOPE_AGENT);
        __hip_atomic_store(dst + 2, t.z, __ATOMIC_RELAXED, __HIP_MEMORY_SCOPE_AGENT);
        __hip_atomic_store(dst + 3, t.w, __ATOMIC_RELAXED, __HIP_MEMORY_SCOPE_AGENT);
    }
    __syncthreads();

    // Publish flag (release), then bounded spin on partner's flag (acquire).
    if (tid == 0) {
        __hip_atomic_fetch_add(&flags[my_slot], 1u, __ATOMIC_RELEASE,
                               __HIP_MEMORY_SCOPE_AGENT);
        unsigned int spins = 0;
        int ok = 1;
        while ((__hip_atomic_load(&flags[oth_slot], __ATOMIC_ACQUIRE,
                                  __HIP_MEMORY_SCOPE_AGENT) - base) == 0u) {
            if (++spins > SPIN_LIMIT) { ok = 0; break; }
        }
        sh_timeout = !ok;
    }
    __syncthreads();

    if (!sh_timeout) {
        // Fast path: partner's partial from ws (L2-resident, same XCD).
        if (tid < 32) {
            const int which = tid >> 4;
            const int c     = tid & 15;
            const float* src = wsf + ((size_t)oth_slot * 2 + which) * 64 + c * 4;
            float4 t;
            t.x = __hip_atomic_load(src + 0, __ATOMIC_RELAXED, __HIP_MEMORY_SCOPE_AGENT);
            t.y = __hip_atomic_load(src + 1, __ATOMIC_RELAXED, __HIP_MEMORY_SCOPE_AGENT);
            t.z = __hip_atomic_load(src + 2, __ATOMIC_RELAXED, __HIP_MEMORY_SCOPE_AGENT);
            t.w = __hip_atomic_load(src + 3, __ATOMIC_RELAXED, __HIP_MEMORY_SCOPE_AGENT);
            fsum_oth[which][c] = t;
        }
    } else {
        // Timeout fallback: read partner's half directly (round-1 behavior).
        const int r_oth0 = (1 - half) * 512 + rg;
        float4 su2 = make_float4(0.f, 0.f, 0.f, 0.f);
        float4 sv2 = make_float4(0.f, 0.f, 0.f, 0.f);
        #pragma unroll
        for (int i = 0; i < 8; ++i) {
            size_t ix = (size_t)(r_oth0 + 64 * i) * 16 + k4;
            float4 a = ub[ix];
            float4 b = vb[ix];
            su2.x += a.x; su2.y += a.y; su2.z += a.z; su2.w += a.w;
            sv2.x += b.x; sv2.y += b.y; sv2.z += b.z; sv2.w += b.w;
        }
        su2.x += __shfl_xor(su2.x, 16); su2.y += __shfl_xor(su2.y, 16);
        su2.z += __shfl_xor(su2.z, 16); su2.w += __shfl_xor(su2.w, 16);
        su2.x += __shfl_xor(su2.x, 32); su2.y += __shfl_xor(su2.y, 32);
        su2.z += __shfl_xor(su2.z, 32); su2.w += __shfl_xor(su2.w, 32);
        sv2.x += __shfl_xor(sv2.x, 16); sv2.y += __shfl_xor(sv2.y, 16);
        sv2.z += __shfl_xor(sv2.z, 16); sv2.w += __shfl_xor(sv2.w, 16);
        sv2.x += __shfl_xor(sv2.x, 32); sv2.y += __shfl_xor(sv2.y, 32);
        sv2.z += __shfl_xor(sv2.z, 32); sv2.w += __shfl_xor(sv2.w, 32);
        if ((tid & 63) < 16) {
            red_u[wave][k4] = su2;
            red_v[wave][k4] = sv2;
        }
        __syncthreads();
        if (tid < 32) {
            const int which = tid >> 4;
            const int c     = tid & 15;
            float4 t = make_float4(0.f, 0.f, 0.f, 0.f);
            if (which == 0) {
                #pragma unroll
                for (int i = 0; i < 16; ++i) {
                    float4 b = red_v[i][c];
                    t.x += b.x; t.y += b.y; t.z += b.z; t.w += b.w;
                }
            } else {
                #pragma unroll
                for (int i = 0; i < 16; ++i) {
                    float4 a = red_u[i][c];
                    t.x += a.x; t.y += a.y; t.z += a.z; t.w += a.w;
                }
            }
            fsum_oth[which][c] = t;
        }
    }
    __syncthreads();

    const float4 vs = make_float4(fsum_own[0][k4].x + fsum_oth[0][k4].x,
                                  fsum_own[0][k4].y + fsum_oth[0][k4].y,
                                  fsum_own[0][k4].z + fsum_oth[0][k4].z,
                                  fsum_own[0][k4].w + fsum_oth[0][k4].w);  // masks u
    const float4 us = make_float4(fsum_own[1][k4].x + fsum_oth[1][k4].x,
                                  fsum_own[1][k4].y + fsum_oth[1][k4].y,
                                  fsum_own[1][k4].z + fsum_oth[1][k4].z,
                                  fsum_own[1][k4].w + fsum_oth[1][k4].w);  // masks v

    // ---- Phase B: mask own half from registers, streaming stores ----------
    float* ou = out + (size_t)batch * NROW * KDIM;
    float* ov = out + ELEMS_PER_TENSOR + (size_t)batch * NROW * KDIM;

    #pragma unroll
    for (int i = 0; i < 8; ++i) {
        size_t io = (size_t)(r_own0 + 64 * i) * 16 + k4;

        float pu = ur[i].x * vs.x + ur[i].y * vs.y + ur[i].z * vs.z + ur[i].w * vs.w;
        pu += __shfl_xor(pu, 1);
        pu += __shfl_xor(pu, 2);
        pu += __shfl_xor(pu, 4);
        pu += __shfl_xor(pu, 8);
        float mu = (pu > 0.f) ? 1.f : 0.f;
        floatx4 outu = { ur[i].x * mu, ur[i].y * mu, ur[i].z * mu, ur[i].w * mu };
        __builtin_nontemporal_store(outu, (floatx4*)(ou + io * 4));

        float pv = vr[i].x * us.x + vr[i].y * us.y + vr[i].z * us.z + vr[i].w * us.w;
        pv += __shfl_xor(pv, 1);
        pv += __shfl_xor(pv, 2);
        pv += __shfl_xor(pv, 4);
        pv += __shfl_xor(pv, 8);
        float mv = (pv > 0.f) ? 1.f : 0.f;
        floatx4 outv = { vr[i].x * mv, vr[i].y * mv, vr[i].z * mv, vr[i].w * mv };
        __builtin_nontemporal_store(outv, (floatx4*)(ov + io * 4));
    }
}

// ---- Fallback (round-1 kernel): used only if ws is too small --------------
__global__ __launch_bounds__(1024)
void fused_local_kernel(const float* __restrict__ u,
                        const float* __restrict__ v,
                        float* __restrict__ out) {
    const int bid   = blockIdx.x;
    const int xcd   = bid & 7;
    const int slot  = bid >> 3;
    const int batch = xcd * 16 + (slot >> 1);
    const int half  = slot & 1;
    const int tid   = threadIdx.x;
    const int k4    = tid & 15;
    const int rg    = tid >> 4;
    const int wave  = tid >> 6;

    const float4* ub = (const float4*)(u + (size_t)batch * NROW * KDIM);
    const float4* vb = (const float4*)(v + (size_t)batch * NROW * KDIM);

    const int r_own0 = half * 512 + rg;
    const int r_oth0 = (1 - half) * 512 + rg;

    float4 ur[8], vr[8];
    float4 su = make_float4(0.f, 0.f, 0.f, 0.f);
    float4 sv = make_float4(0.f, 0.f, 0.f, 0.f);
    #pragma unroll
    for (int i = 0; i < 8; ++i) {
        size_t io = (size_t)(r_own0 + 64 * i) * 16 + k4;
        ur[i] = ub[io];
        vr[i] = vb[io];
        su.x += ur[i].x; su.y += ur[i].y; su.z += ur[i].z; su.w += ur[i].w;
        sv.x += vr[i].x; sv.y += vr[i].y; sv.z += vr[i].z; sv.w += vr[i].w;
    }
    #pragma unroll
    for (int i = 0; i < 8; ++i) {
        size_t ix = (size_t)(r_oth0 + 64 * i) * 16 + k4;
        float4 a = ub[ix];
        float4 b = vb[ix];
        su.x += a.x; su.y += a.y; su.z += a.z; su.w += a.w;
        sv.x += b.x; sv.y += b.y; sv.z += b.z; sv.w += b.w;
    }

    su.x += __shfl_xor(su.x, 16); su.y += __shfl_xor(su.y, 16);
    su.z += __shfl_xor(su.z, 16); su.w += __shfl_xor(su.w, 16);
    su.x += __shfl_xor(su.x, 32); su.y += __shfl_xor(su.y, 32);
    su.z += __shfl_xor(su.z, 32); su.w += __shfl_xor(su.w, 32);
    sv.x += __shfl_xor(sv.x, 16); sv.y += __shfl_xor(sv.y, 16);
    sv.z += __shfl_xor(sv.z, 16); sv.w += __shfl_xor(sv.w, 16);
    sv.x += __shfl_xor(sv.x, 32); sv.y += __shfl_xor(sv.y, 32);
    sv.z += __shfl_xor(sv.z, 32); sv.w += __shfl_xor(sv.w, 32);

    __shared__ float4 red_u[16][16];
    __shared__ float4 red_v[16][16];
    __shared__ float4 fsum[2][16];
    if ((tid & 63) < 16) {
        red_u[wave][k4] = su;
        red_v[wave][k4] = sv;
    }
    __syncthreads();

    if (tid < 32) {
        const int which = tid >> 4;
        const int c     = tid & 15;
        float4 t = make_float4(0.f, 0.f, 0.f, 0.f);
        if (which == 0) {
            #pragma unroll
            for (int i = 0; i < 16; ++i) {
                float4 b = red_v[i][c];
                t.x += b.x; t.y += b.y; t.z += b.z; t.w += b.w;
            }
        } else {
            #pragma unroll
            for (int i = 0; i < 16; ++i) {
                float4 a = red_u[i][c];
                t.x += a.x; t.y += a.y; t.z += a.z; t.w += a.w;
            }
        }
        fsum[which][c] = t;
    }
    __syncthreads();

    const float4 vs = fsum[0][k4];
    const float4 us = fsum[1][k4];

    float* ou = out + (size_t)batch * NROW * KDIM;
    float* ov = out + ELEMS_PER_TENSOR + (size_t)batch * NROW * KDIM;

    #pragma unroll
    for (int i = 0; i < 8; ++i) {
        size_t io = (size_t)(r_own0 + 64 * i) * 16 + k4;

        float pu = ur[i].x * vs.x + ur[i].y * vs.y + ur[i].z * vs.z + ur[i].w * vs.w;
        pu += __shfl_xor(pu, 1);
        pu += __shfl_xor(pu, 2);
        pu += __shfl_xor(pu, 4);
        pu += __shfl_xor(pu, 8);
        float mu = (pu > 0.f) ? 1.f : 0.f;
        floatx4 outu = { ur[i].x * mu, ur[i].y * mu, ur[i].z * mu, ur[i].w * mu };
        __builtin_nontemporal_store(outu, (floatx4*)(ou + io * 4));

        float pv = vr[i].x * us.x + vr[i].y * us.y + vr[i].z * us.z + vr[i].w * us.w;
        pv += __shfl_xor(pv, 1);
        pv += __shfl_xor(pv, 2);
        pv += __shfl_xor(pv, 4);
        pv += __shfl_xor(pv, 8);
        float mv = (pv > 0.f) ? 1.f : 0.f;
        floatx4 outv = { vr[i].x * mv, vr[i].y * mv, vr[i].z * mv, vr[i].w * mv };
        __builtin_nontemporal_store(outv, (floatx4*)(ov + io * 4));
    }
}

extern "C" void kernel_launch(void* const* d_in, const int* in_sizes, int n_in,
                              void* d_out, int out_size, void* d_ws, size_t ws_size,
                              hipStream_t stream) {
    const float* u = (const float*)d_in[0];
    const float* v = (const float*)d_in[1];
    float* out = (float*)d_out;

    if (d_ws != nullptr && ws_size >= WS_BYTES) {
        float* wsf = (float*)d_ws;
        unsigned int* flags = (unsigned int*)((char*)d_ws + (size_t)WS_PAYLOAD_FLOATS * 4);
        fused_pair_kernel<<<dim3(256), dim3(1024), 0, stream>>>(u, v, out, wsf, flags);
    } else {
        fused_local_kernel<<<dim3(256), dim3(1024), 0, stream>>>(u, v, out);
    }
}